// Round 6
// baseline (576.687 us; speedup 1.0000x reference)
//
#include <hip/hip_runtime.h>

#define B_ 4
#define L_ 2000
#define LP 2048       // padded length for Q/K/V buffers
#define C_ 512
#define H_ 8
#define HD 64
#define CHUNK_ 1000

typedef __attribute__((ext_vector_type(8))) short bf16x8;
typedef __attribute__((ext_vector_type(4))) float f32x4;

__device__ inline unsigned short f2bf(float f) {
    union { float f; unsigned int u; } v; v.f = f;
    unsigned int r = v.u + 0x7fffu + ((v.u >> 16) & 1u);
    return (unsigned short)(r >> 16);
}

// -------------------------------------------------------------------------
// conv (depthwise k=3, zero pad at 1000-chunk boundaries) + residual + bias,
// bf16 out; also emits x cast to bf16. Vectorized x4 over channels.
// -------------------------------------------------------------------------
__global__ void conv_kernel(const float* __restrict__ x, const float* __restrict__ Wl,
                            const float* __restrict__ bl,
                            unsigned short* __restrict__ kv16,
                            unsigned short* __restrict__ x16) {
    int i4 = blockIdx.x * 256 + threadIdx.x;
    if (i4 >= B_ * L_ * C_ / 4) return;
    int idx = i4 * 4;
    int c = idx & (C_ - 1);
    int l = (idx >> 9) % L_;
    int p = l % CHUNK_;
    float4 xc = *(const float4*)&x[idx];
    float4 lf = (p > 0)          ? *(const float4*)&x[idx - C_] : make_float4(0, 0, 0, 0);
    float4 rt = (p < CHUNK_ - 1) ? *(const float4*)&x[idx + C_] : make_float4(0, 0, 0, 0);
    float y[4];
    const float* xcp = &xc.x; const float* lfp = &lf.x; const float* rtp = &rt.x;
#pragma unroll
    for (int j = 0; j < 4; j++) {
        y[j] = xcp[j] + bl[c + j] + Wl[(c + j) * 3 + 0] * lfp[j]
             + Wl[(c + j) * 3 + 1] * xcp[j] + Wl[(c + j) * 3 + 2] * rtp[j];
    }
    ushort4 kv = make_ushort4(f2bf(y[0]), f2bf(y[1]), f2bf(y[2]), f2bf(y[3]));
    ushort4 xo = make_ushort4(f2bf(xcp[0]), f2bf(xcp[1]), f2bf(xcp[2]), f2bf(xcp[3]));
    *(ushort4*)&kv16[idx] = kv;
    *(ushort4*)&x16[idx]  = xo;
}

// Both weight tensors cast in one launch (x4 vectorized).
__global__ void cvt_kernel(const float* __restrict__ Wq, const float* __restrict__ Wkv,
                           unsigned short* __restrict__ Wq16,
                           unsigned short* __restrict__ Wkv16) {
    int i4 = blockIdx.x * 256 + threadIdx.x;
    int idx = i4 * 4;
    const float* src; unsigned short* dst; int off;
    if (idx < 262144) { src = Wq; dst = Wq16; off = idx; }
    else if (idx < 786432) { src = Wkv; dst = Wkv16; off = idx - 262144; }
    else return;
    float4 v = *(const float4*)&src[off];
    *(ushort4*)&dst[off] = make_ushort4(f2bf(v.x), f2bf(v.y), f2bf(v.z), f2bf(v.w));
}

// -------------------------------------------------------------------------
// Projection GEMM via MFMA, both projections in ONE launch.
// y<8:  Q = x16 @ Wq  -> [bh][2048][64]
// y>=8: KV = kv16 @ Wkv; n<512 -> K [bh][2048][64]; else V^T [bh][64][2048]
// -------------------------------------------------------------------------
__global__ __launch_bounds__(256) void proj_mfma(
    const unsigned short* __restrict__ x16, const unsigned short* __restrict__ kv16,
    const unsigned short* __restrict__ Wq16, const unsigned short* __restrict__ Wkv16,
    const float* __restrict__ bq, const float* __restrict__ bkv,
    unsigned short* __restrict__ Q16, unsigned short* __restrict__ K16,
    unsigned short* __restrict__ V16) {
    __shared__ __align__(16) unsigned short tile[64][72];
    const int tid = threadIdx.x;
    const int lane = tid & 63;
    const int wave = tid >> 6;
    const int c = lane & 15;
    const int quad = lane >> 4;
    const bool qpath = blockIdx.y < 8;
    const unsigned short* A = qpath ? x16 : kv16;
    const unsigned short* W = qpath ? Wq16 : Wkv16;
    const float* bias = qpath ? bq : bkv;
    const int n0 = (qpath ? blockIdx.y : (blockIdx.y - 8)) * 64;
    const int mrow = blockIdx.x * 64 + wave * 16 + c;
    f32x4 acc[4] = {{0,0,0,0},{0,0,0,0},{0,0,0,0},{0,0,0,0}};
    const unsigned short* Ap = A + (size_t)mrow * C_ + quad * 8;
#pragma unroll 4
    for (int k0 = 0; k0 < C_; k0 += 32) {
        bf16x8 a = *(const bf16x8*)(Ap + k0);
#pragma unroll
        for (int t = 0; t < 4; t++) {
            bf16x8 wv = *(const bf16x8*)&W[(size_t)(n0 + 16 * t + c) * C_ + k0 + quad * 8];
            acc[t] = __builtin_amdgcn_mfma_f32_16x16x32_bf16(a, wv, acc[t], 0, 0, 0);
        }
    }
    const bool vpath = (!qpath) && (n0 >= C_);
    const int lm = wave * 16 + quad * 4;
#pragma unroll
    for (int t = 0; t < 4; t++) {
        float bv = bias[n0 + 16 * t + c];
#pragma unroll
        for (int r = 0; r < 4; r++) {
            unsigned short val = f2bf(acc[t][r] + bv);
            if (!vpath) tile[lm + r][16 * t + c] = val;   // [m][n]
            else        tile[16 * t + c][lm + r] = val;   // [n][m] transpose
        }
    }
    __syncthreads();
    if (!vpath) {
        unsigned short* o0 = qpath ? Q16 : K16;
        int lr = tid >> 2, chunk = (tid & 3) * 16;
        int m = blockIdx.x * 64 + lr;
        int b = m / L_, l = m % L_;
        int nn = (n0 + chunk) & (C_ - 1);
        int h = nn >> 6, d0 = nn & 63;
        unsigned short* dst = &o0[(((size_t)(b * H_ + h) * LP) + l) * HD + d0];
        *(uint4*)dst       = *(const uint4*)&tile[lr][chunk];
        *(uint4*)(dst + 8) = *(const uint4*)&tile[lr][chunk + 8];
    } else {
        int dr = tid >> 2, chunk = (tid & 3) * 16;
        int nn = (n0 - C_) + dr;
        int h = nn >> 6, d = nn & 63;
        int mbase = blockIdx.x * 64 + chunk;
        int b0 = mbase / L_, b1 = (mbase + 15) / L_;
        if (b0 == b1) {
            int l = mbase % L_;
            unsigned short* dst = &V16[(((size_t)(b0 * H_ + h) * HD) + d) * LP + l];
            *(uint4*)dst       = *(const uint4*)&tile[dr][chunk];
            *(uint4*)(dst + 8) = *(const uint4*)&tile[dr][chunk + 8];
        } else {
            for (int i = 0; i < 16; i++) {
                int m = mbase + i;
                int b = m / L_, l = m % L_;
                V16[(((size_t)(b * H_ + h) * HD) + d) * LP + l] = tile[dr][chunk + i];
            }
        }
    }
}

// -------------------------------------------------------------------------
// Flash attention, bf16 MFMA, BARRIER-FREE. One wave = 16 rows x all 4
// batches of (h, ks-half). K/V B-fragments are wave-invariant -> read
// directly from global (L1/L2-hot, shared across waves & row-tile blocks).
// rpe read once kernel-wide (b-shared in registers), depth-1 prefetched.
// P goes through a tiny per-wave LDS strip (C-layout -> A-layout).
// LDS = 10 KB/block, no __syncthreads: 8 free-running waves/CU.
// grid 512: bid = ks(1) | h(3) | rt(5). Col tiles of 32; ks0: kt 0..30,
// ks1: kt 31..62 (last tile half-masked via rpe = -1e30).
// -------------------------------------------------------------------------
__global__ __launch_bounds__(256, 2) void attn_mfma(
    const unsigned short* __restrict__ Q, const unsigned short* __restrict__ K,
    const unsigned short* __restrict__ Vt, const float* __restrict__ rpe,
    float* __restrict__ po, float* __restrict__ lsum) {
    __shared__ __align__(16) unsigned short Ps[4][2][16][40];
    const int lane = threadIdx.x & 63;
    const int wave = threadIdx.x >> 6;
    const int c = lane & 15;
    const int quad = lane >> 4;
    const int bid = blockIdx.x;
    const int ks = bid & 1;
    const int h  = (bid >> 1) & 7;
    const int rt = bid >> 4;
    const int r0w = rt * 64 + wave * 16;
    const int rg0 = r0w + quad * 4;
    const float* rb = rpe + (size_t)h * L_ * L_;

    bf16x8 qf0[4], qf1[4];
    const unsigned short* kp[4];   // K + c*HD + quad*8  (per batch)
    const unsigned short* vp[4];   // Vt + c*LP + quad*8 (per batch)
#pragma unroll
    for (int b = 0; b < 4; b++) {
        const unsigned short* Qb = Q + (size_t)(b * H_ + h) * LP * HD;
        qf0[b] = *(const bf16x8*)&Qb[(size_t)(r0w + c) * HD + quad * 8];
        qf1[b] = *(const bf16x8*)&Qb[(size_t)(r0w + c) * HD + 32 + quad * 8];
        kp[b] = K  + (size_t)(b * H_ + h) * LP * HD + c * HD + quad * 8;
        vp[b] = Vt + (size_t)(b * H_ + h) * HD * LP + c * LP + quad * 8;
    }

    float l_i[4][4] = {};
    f32x4 o_acc[4][4];
#pragma unroll
    for (int b = 0; b < 4; b++)
#pragma unroll
        for (int t = 0; t < 4; t++) o_acc[b][t] = (f32x4){0.f, 0.f, 0.f, 0.f};

    const int kt0 = ks ? 31 : 0;
    const int kt1 = ks ? 63 : 31;

    // prologue: rpe for first iteration (log2e folded; first tile never col-edge)
    float rpl[4][2];
    {
        const int c0 = kt0 * 32;
        const bool redge = (rt == 31);
#pragma unroll
        for (int r = 0; r < 4; r++) {
            const int rg = rg0 + r;
            const int rgc = redge ? min(rg, L_ - 1) : rg;
#pragma unroll
            for (int t = 0; t < 2; t++) {
                float raw = rb[(size_t)rgc * L_ + c0 + 16 * t + c];
                rpl[r][t] = (!redge || rg < L_) ? raw * 1.44269504f : 0.f;
            }
        }
    }

    for (int kt = kt0; kt < kt1; kt++) {
        const int c0 = kt * 32;

        // ---- prefetch next iteration's rpe (masking folded in) ----
        float rpn[4][2];
        if (kt + 1 < kt1) {
            const int c1 = c0 + 32;
            const bool edge = (rt == 31) || (kt + 1 == 62);
            if (!edge) {
#pragma unroll
                for (int r = 0; r < 4; r++)
#pragma unroll
                    for (int t = 0; t < 2; t++)
                        rpn[r][t] = rb[(size_t)(rg0 + r) * L_ + c1 + 16 * t + c]
                                    * 1.44269504f;
            } else {
#pragma unroll
                for (int r = 0; r < 4; r++) {
                    const int rg = rg0 + r;
                    const int rgc = min(rg, L_ - 1);
#pragma unroll
                    for (int t = 0; t < 2; t++) {
                        const int col = c1 + 16 * t + c;
                        float raw = rb[(size_t)rgc * L_ + min(col, L_ - 1)];
                        rpn[r][t] = (col >= L_) ? -1e30f
                                   : ((rg < L_) ? raw * 1.44269504f : 0.f);
                    }
                }
            }
        }

        // ---- 4 independent batch chains; K/V direct from L1/L2 ----
#pragma unroll
        for (int b = 0; b < 4; b++) {
            // S = Q K^T (16 rows x 32 cols, K-dim 64)
            f32x4 s[2];
#pragma unroll
            for (int t = 0; t < 2; t++) {
                const unsigned short* kbp = kp[b] + (size_t)(c0 + 16 * t) * HD;
                bf16x8 k0f = *(const bf16x8*)kbp;
                bf16x8 k1f = *(const bf16x8*)(kbp + 32);
                f32x4 z = {0.f, 0.f, 0.f, 0.f};
                z = __builtin_amdgcn_mfma_f32_16x16x32_bf16(qf0[b], k0f, z, 0, 0, 0);
                z = __builtin_amdgcn_mfma_f32_16x16x32_bf16(qf1[b], k1f, z, 0, 0, 0);
                s[t] = z;
            }
            // p = exp2(s*scale*log2e + rpe*log2e); lane-local l; P -> LDS
#pragma unroll
            for (int r = 0; r < 4; r++) {
                float psum = 0.f;
#pragma unroll
                for (int t = 0; t < 2; t++) {
                    float p = exp2f(fmaf(s[t][r], 0.18033688f, rpl[r][t]));
                    psum += p;
                    Ps[wave][b & 1][quad * 4 + r][16 * t + c] = f2bf(p);
                }
                l_i[b][r] += psum;
            }
            // O += P V (K-dim 32)
            bf16x8 pa = *(const bf16x8*)&Ps[wave][b & 1][c][quad * 8];
#pragma unroll
            for (int t = 0; t < 4; t++) {
                bf16x8 vf = *(const bf16x8*)(vp[b] + (size_t)(16 * t) * LP + c0);
                o_acc[b][t] = __builtin_amdgcn_mfma_f32_16x16x32_bf16(pa, vf, o_acc[b][t], 0, 0, 0);
            }
        }
#pragma unroll
        for (int r = 0; r < 4; r++) { rpl[r][0] = rpn[r][0]; rpl[r][1] = rpn[r][1]; }
    }

    // ---- epilogue: reduce l over 16 c-lanes; store raw partials ----
#pragma unroll
    for (int b = 0; b < 4; b++) {
#pragma unroll
        for (int r = 0; r < 4; r++) {
            float v = l_i[b][r];
            v += __shfl_xor(v, 1);
            v += __shfl_xor(v, 2);
            v += __shfl_xor(v, 4);
            v += __shfl_xor(v, 8);
            l_i[b][r] = v;
        }
        float* pob = po + (size_t)(ks * 32 + b * H_ + h) * L_ * HD;
#pragma unroll
        for (int t = 0; t < 4; t++) {
            int d = 16 * t + c;
#pragma unroll
            for (int r = 0; r < 4; r++) {
                int l = rg0 + r;
                if (l < L_) pob[(size_t)l * HD + d] = o_acc[b][t][r];
            }
        }
        if (c == 0) {
            float* lb = lsum + (size_t)(ks * 32 + b * H_ + h) * LP;
#pragma unroll
            for (int r = 0; r < 4; r++) lb[rg0 + r] = l_i[b][r];
        }
    }
}

// -------------------------------------------------------------------------
// Merge: out[bh][d][l] = (po0+po1)[bh][l][d] / (l0+l1)[bh][l], LDS transpose.
// -------------------------------------------------------------------------
__global__ __launch_bounds__(256) void merge_kernel(
    const float* __restrict__ po, const float* __restrict__ lsum,
    float* __restrict__ out) {
    __shared__ __align__(16) float T[64][68];
    const int tid = threadIdx.x;
    const int bh = blockIdx.x >> 5;
    const int lt = blockIdx.x & 31;
    const float* p0 = po + (size_t)bh * L_ * HD;
    const float* p1 = p0 + (size_t)32 * L_ * HD;
    const float* ls0 = lsum + (size_t)bh * LP;
    const float* ls1 = ls0 + (size_t)32 * LP;
#pragma unroll
    for (int it = 0; it < 4; it++) {
        int idx = it * 256 + tid;
        int row = idx >> 4;
        int dc = (idx & 15) * 4;
        int l = lt * 64 + row;
        float4 v = make_float4(0.f, 0.f, 0.f, 0.f);
        if (l < L_) {
            float4 a  = *(const float4*)&p0[(size_t)l * HD + dc];
            float4 b4 = *(const float4*)&p1[(size_t)l * HD + dc];
            float inv = 1.f / (ls0[l] + ls1[l]);
            v = make_float4((a.x + b4.x) * inv, (a.y + b4.y) * inv,
                            (a.z + b4.z) * inv, (a.w + b4.w) * inv);
        }
        T[dc + 0][row] = v.x; T[dc + 1][row] = v.y;
        T[dc + 2][row] = v.z; T[dc + 3][row] = v.w;
    }
    __syncthreads();
    const int d = tid >> 2, ch = (tid & 3) * 16;
    const int lbase = lt * 64 + ch;
    if (lbase + 15 < L_) {
        float* dst = &out[((size_t)(bh * HD + d)) * L_ + lbase];
#pragma unroll
        for (int i = 0; i < 4; i++)
            *(float4*)&dst[4 * i] = *(const float4*)&T[d][ch + 4 * i];
    }
}

extern "C" void kernel_launch(void* const* d_in, const int* in_sizes, int n_in,
                              void* d_out, int out_size, void* d_ws, size_t ws_size,
                              hipStream_t stream) {
    const float* x   = (const float*)d_in[0];
    const float* rpe = (const float*)d_in[1];
    const float* Wq  = (const float*)d_in[2];
    const float* bq  = (const float*)d_in[3];
    const float* Wkv = (const float*)d_in[4];
    const float* bkv = (const float*)d_in[5];
    const float* Wl  = (const float*)d_in[6];
    const float* bl  = (const float*)d_in[7];
    float* out = (float*)d_out;

    unsigned short* wsu  = (unsigned short*)d_ws;
    unsigned short* x16  = wsu;                 // 4,096,000
    unsigned short* kv16 = wsu + 4096000;       // 4,096,000
    unsigned short* Wq16 = wsu + 8192000;       //   262,144
    unsigned short* Wkv16= wsu + 8454144;       //   524,288
    unsigned short* Q16  = wsu + 8978432;       // 4,194,304  [bh][2048][64]
    unsigned short* K16  = wsu + 13172736;      // 4,194,304  [bh][2048][64]
    unsigned short* V16  = wsu + 17367040;      // 4,194,304  [bh][64][2048]
    float* po   = (float*)(wsu + 21561344);     // 8,192,000 fp32 [2][32][2000][64]
    float* lsum = po + 8192000;                 //   131,072 fp32 [2][32][2048]

    conv_kernel<<<(B_ * L_ * C_ / 4 + 255) / 256, 256, 0, stream>>>(x, Wl, bl, kv16, x16);
    cvt_kernel<<<(786432 / 4 + 255) / 256, 256, 0, stream>>>(Wq, Wkv, Wq16, Wkv16);
    proj_mfma<<<dim3(125, 24), 256, 0, stream>>>(x16, kv16, Wq16, Wkv16, bq, bkv,
                                                 Q16, K16, V16);
    attn_mfma<<<512, 256, 0, stream>>>(Q16, K16, V16, rpe, po, lsum);
    merge_kernel<<<1024, 256, 0, stream>>>(po, lsum, out);
}